// Round 4
// baseline (319.790 us; speedup 1.0000x reference)
//
#include <hip/hip_runtime.h>

// Problem constants
#define B_SZ   8
#define S_LEN  1024
#define D_MOD  256
#define NHEADS 8
#define M_ROWS 8192
#define LOG2E  1.4426950408889634f
#define QSCALE_LOG2E 0.2550352766751165f   // (1/sqrt(32)) * log2(e)

typedef _Float16 f16x8 __attribute__((ext_vector_type(8)));
typedef _Float16 f16x4 __attribute__((ext_vector_type(4)));
typedef float    f32x4 __attribute__((ext_vector_type(4)));

// ---------------------------------------------------------------------------
// One-shot grid barrier (counters zeroed per replay by a hipMemsetAsync node).
// Release: __syncthreads (compiler drains vmcnt before s_barrier) puts all
// block stores in L2; tid0's __threadfence() does the device-scope L2
// writeback (cross-XCD visibility, G16). Acquire: post-spin __threadfence()
// invalidates this CU/XCD's caches before any thread reads.
// Co-residency of all 512 blocks is guaranteed: __launch_bounds__(256,2)
// => 2 blocks/CU x 256 CUs, LDS 33.8KB/block (2x1.6=67.6KB <= 160KB).
// ---------------------------------------------------------------------------
__device__ __forceinline__ void grid_barrier(int* cnt, int target) {
    __syncthreads();
    if (threadIdx.x == 0) {
        __threadfence();
        atomicAdd(cnt, 1);
        while (__hip_atomic_load(cnt, __ATOMIC_ACQUIRE, __HIP_MEMORY_SCOPE_AGENT) < target)
            __builtin_amdgcn_s_sleep(2);
        __threadfence();
    }
    __syncthreads();
}

// ---------------------------------------------------------------------------
// MEGA KERNEL: prep | QKV GEMM | flash attention | out GEMM in ONE launch.
// Eliminates 3 full graph-node boundaries (drain + launch + dispatch ramp).
// Phase bodies are byte-identical to the round-3 4-kernel version.
// ---------------------------------------------------------------------------
__global__ __launch_bounds__(256, 2)
void mega_kernel(const float* __restrict__ in_q, const float* __restrict__ in_kv,
                 const float* __restrict__ Wq, const float* __restrict__ bq,
                 const float* __restrict__ Wk, const float* __restrict__ bk,
                 const float* __restrict__ Wv, const float* __restrict__ bv,
                 const float* __restrict__ rel, const float* __restrict__ Wo,
                 const float* __restrict__ bo, float* __restrict__ out,
                 _Float16* __restrict__ qs, _Float16* __restrict__ ks,
                 _Float16* __restrict__ vs, _Float16* __restrict__ xh,
                 _Float16* __restrict__ wtp, _Float16* __restrict__ tab,
                 int* __restrict__ bar) {
    __shared__ __align__(16) _Float16 SMEM[64 * 264];   // 33,792 B union

    const int bid  = blockIdx.x;
    const int tid  = threadIdx.x;
    const int w    = tid >> 6;
    const int lane = tid & 63;
    const int quad = lane >> 4;
    const int l16  = lane & 15;

    // ============ phase 1: prep (blocks 0..94; rest idle) ============
    if (bid < 32) {
        // pack 4 fp32 W mats -> fragment-ordered fp16 wtp
        _Float16* Wl = SMEM;               // [32][264]
        const int mi = bid >> 3;
        const int k0 = (bid & 7) << 5;
        const float* W = (mi == 0) ? Wq : (mi == 1) ? Wk : (mi == 2) ? Wv : Wo;
        {
            const int r  = tid >> 3;
            const int c4 = (tid & 7) * 4;
            const float* src = W + (size_t)(k0 + r) * 256 + c4;
#pragma unroll
            for (int g = 0; g < 8; ++g) {
                f32x4 v = *(const f32x4*)(src + g * 32);
                f16x4 o;
#pragma unroll
                for (int j = 0; j < 4; ++j) o[j] = (_Float16)v[j];
                *(f16x4*)(&Wl[r * 264 + c4 + g * 32]) = o;
            }
        }
        __syncthreads();
        const int n16 = tid >> 4;
        const int kk  = k0 >> 5;
#pragma unroll
        for (int q2 = 0; q2 < 4; ++q2) {
            f16x8 v;
#pragma unroll
            for (int j = 0; j < 8; ++j) v[j] = Wl[(q2 * 8 + j) * 264 + n16 * 16 + l16];
            *(f16x8*)(wtp + (((size_t)(mi * 16 + n16) * 8 + kk) << 9) + (q2 * 16 + l16) * 8) = v;
        }
    } else if (bid < 95) {
        // fp16 bias C-init table: one block per dy31
        float* rl = (float*)SMEM;          // [63][8]
        const int dy31 = bid - 32;
        for (int f = tid; f < 504; f += 256) rl[f] = rel[(size_t)dy31 * 504 + f];
        __syncthreads();
        const int h  = tid >> 5;
        const int r5 = tid & 31;
#pragma unroll
        for (int c = 0; c < 6; ++c) {
            const int oi   = r5 * 6 + c;       // 0..191
            const int e    = oi >> 6;
            const int ln   = oi & 63;
            const int qd   = ln >> 4, lo = ln & 15;
            f16x4 v;
#pragma unroll
            for (int reg = 0; reg < 4; ++reg) {
                const int idx = 16 * e + lo - qd * 4 - reg + 15;   // in [0,62]
                v[reg] = (_Float16)(rl[idx * 8 + h] * LOG2E);
            }
            *(f16x4*)(tab + (((size_t)(h * 63 + dy31) * 3 + e) << 8) + ln * 4) = v;
        }
    }
    grid_barrier(bar + 0, 512);

    // ============ phase 2: QKV GEMM (each block: z=0 then z=1) ============
    {
        _Float16* As = SMEM;               // [64][264]
        _Float16* Ta = SMEM;               // [act64][hd 72]
        _Float16* Tb = SMEM + 64 * 72;     // [hd64][key 72]
        const int m0 = (bid & 127) * 64;
        const int n0 = ((bid >> 7) & 3) * 64;
        const int b = m0 >> 10, mloc = m0 & 1023;

        for (int z = 0; z < 2; ++z) {
            __syncthreads();               // LDS reuse across z iterations
            // stage A tile 64x256 fp32 -> fp16
            {
                const int r  = tid >> 2;
                const int c4 = (tid & 3) * 4;
                const float* src = (z ? in_kv : in_q) + (size_t)(m0 + r) * 256 + c4;
                _Float16* dst = As + r * 264 + c4;
#pragma unroll
                for (int g = 0; g < 16; ++g) {
                    f32x4 v = *(const f32x4*)(src + g * 16);
                    f16x4 o;
#pragma unroll
                    for (int j = 0; j < 4; ++j) o[j] = (_Float16)v[j];
                    *(f16x4*)(dst + g * 16) = o;
                }
            }
            __syncthreads();

            const int n16base = (n0 >> 4) + (w >> 1) * 2;
            const int mA = z ? 1 : 0;
            const _Float16* wA0 = wtp + (((size_t)(mA * 16 + n16base + 0) * 8) << 9) + lane * 8;
            const _Float16* wA1 = wtp + (((size_t)(mA * 16 + n16base + 1) * 8) << 9) + lane * 8;
            const _Float16* wV0 = wtp + (((size_t)(2 * 16 + n16base + 0) * 8) << 9) + lane * 8;
            const _Float16* wV1 = wtp + (((size_t)(2 * 16 + n16base + 1) * 8) << 9) + lane * 8;
            const _Float16* arow0 = As + ((w & 1) * 32 + l16) * 264;
            const _Float16* arow1 = arow0 + 16 * 264;

            f32x4 accA[2][2], accV[2][2];
#pragma unroll
            for (int i = 0; i < 2; ++i)
#pragma unroll
                for (int j = 0; j < 2; ++j) {
                    accA[i][j] = (f32x4){0.f, 0.f, 0.f, 0.f};
                    accV[i][j] = (f32x4){0.f, 0.f, 0.f, 0.f};
                }

#pragma unroll
            for (int kk = 0; kk < 8; ++kk) {
                const int k8 = kk * 32 + quad * 8;
                f16x8 a0 = *(const f16x8*)(arow0 + k8);
                f16x8 a1 = *(const f16x8*)(arow1 + k8);
                f16x8 w0 = *(const f16x8*)(wA0 + kk * 512);
                f16x8 w1 = *(const f16x8*)(wA1 + kk * 512);
                // swapped: D[m=hd][n=act]
                accA[0][0] = __builtin_amdgcn_mfma_f32_16x16x32_f16(w0, a0, accA[0][0], 0, 0, 0);
                accA[0][1] = __builtin_amdgcn_mfma_f32_16x16x32_f16(w0, a1, accA[0][1], 0, 0, 0);
                accA[1][0] = __builtin_amdgcn_mfma_f32_16x16x32_f16(w1, a0, accA[1][0], 0, 0, 0);
                accA[1][1] = __builtin_amdgcn_mfma_f32_16x16x32_f16(w1, a1, accA[1][1], 0, 0, 0);
                if (z == 1) {
                    f16x8 v0 = *(const f16x8*)(wV0 + kk * 512);
                    f16x8 v1 = *(const f16x8*)(wV1 + kk * 512);
                    // normal: D[m=key][n=hd]
                    accV[0][0] = __builtin_amdgcn_mfma_f32_16x16x32_f16(a0, v0, accV[0][0], 0, 0, 0);
                    accV[0][1] = __builtin_amdgcn_mfma_f32_16x16x32_f16(a0, v1, accV[0][1], 0, 0, 0);
                    accV[1][0] = __builtin_amdgcn_mfma_f32_16x16x32_f16(a1, v0, accV[1][0], 0, 0, 0);
                    accV[1][1] = __builtin_amdgcn_mfma_f32_16x16x32_f16(a1, v1, accV[1][1], 0, 0, 0);
                }
            }
            __syncthreads();   // As reuse as Ta/Tb

            // epilogue: bias + LDS transpose round-trip -> packed stores
            {
                const float* biasA = z ? bk : bq;
                const float  sc    = z ? 1.0f : QSCALE_LOG2E;
#pragma unroll
                for (int i = 0; i < 2; ++i) {
                    f32x4 b4 = *(const f32x4*)(biasA + n0 + (w >> 1) * 32 + i * 16 + quad * 4);
#pragma unroll
                    for (int jj = 0; jj < 2; ++jj) {
                        f16x4 pk;
#pragma unroll
                        for (int r = 0; r < 4; ++r) pk[r] = (_Float16)((accA[i][jj][r] + b4[r]) * sc);
                        *(f16x4*)(Ta + ((w & 1) * 32 + jj * 16 + l16) * 72 +
                                       (w >> 1) * 32 + i * 16 + quad * 4) = pk;
                    }
                }
                if (z == 1) {
#pragma unroll
                    for (int i = 0; i < 2; ++i) {
                        const float bvv = bv[n0 + (w >> 1) * 32 + i * 16 + l16];
#pragma unroll
                        for (int jj = 0; jj < 2; ++jj) {
                            f16x4 pk;
#pragma unroll
                            for (int r = 0; r < 4; ++r) pk[r] = (_Float16)(accV[jj][i][r] + bvv);
                            *(f16x4*)(Tb + ((w >> 1) * 32 + i * 16 + l16) * 72 +
                                           (w & 1) * 32 + jj * 16 + quad * 4) = pk;
                        }
                    }
                }
            }
            __syncthreads();
            {
                const int l16c = tid & 15, qdc = (tid >> 4) & 3;
                const int tile0 = mloc >> 5;
#pragma unroll
                for (int c2i = 0; c2i < 2; ++c2i) {
                    const int c2 = w * 2 + c2i;
                    const int s2 = c2 >> 2, sub = (c2 >> 1) & 1, hs = c2 & 1;
                    const int bh = b * 8 + (n0 >> 5) + hs;
                    const size_t dbase = (((size_t)(bh * 32 + tile0 + s2) * 2 + sub) << 9) + lane * 8;
                    f16x8 va = *(const f16x8*)(Ta + (s2 * 32 + sub * 16 + l16c) * 72 +
                                                    hs * 32 + qdc * 8);
                    *(f16x8*)((z ? ks : qs) + dbase) = va;
                    if (z == 1) {
                        f16x8 vb = *(const f16x8*)(Tb + (hs * 32 + sub * 16 + l16c) * 72 +
                                                        s2 * 32 + qdc * 8);
                        *(f16x8*)(vs + dbase) = vb;
                    }
                }
            }
        }
    }
    grid_barrier(bar + 1, 512);

    // ============ phase 3: flash attention ============
    {
        _Float16* Ps  = SMEM;              // [4][32][40] = 5120 f16
        _Float16* KVb = SMEM + 5120;       // [2][4][512] = 4096 f16

        const int xcd   = bid & 7;
        const int local = bid >> 3;
        const int bh    = xcd * 8 + (local & 7);
        const int qc    = local >> 3;          // 0..7
        const int b = bh >> 3, h = bh & 7;
        const int qrow_base = qc * 128 + w * 32;
        const int yq = qc * 4 + w;             // q y-tile

        const _Float16* qp = qs + (((size_t)(bh * 32 + yq) * 2) << 9) + lane * 8;
        const f16x8 qf0 = *(const f16x8*)(qp);
        const f16x8 qf1 = *(const f16x8*)(qp + 512);

        // staging chunk: w=0 K-sub0, w=1 K-sub1, w=2 V-sub0, w=3 V-sub1
        const _Float16* kv = ((w < 2) ? ks : vs) + (((size_t)bh * 64) << 9) +
                             (w & 1) * 512 + lane * 8;
        _Float16* myc0 = KVb + (0 * 4 + w) * 512 + lane * 8;
        _Float16* myc1 = KVb + (1 * 4 + w) * 512 + lane * 8;

        const _Float16* tb = tab + (((size_t)h * 189) << 8) + lane * 4;  // +dy31*768

        f16x8 ones;
#pragma unroll
        for (int j = 0; j < 8; ++j) ones[j] = (_Float16)1.0f;

        f32x4 o00 = {0.f,0.f,0.f,0.f}, o01 = {0.f,0.f,0.f,0.f};
        f32x4 o10 = {0.f,0.f,0.f,0.f}, o11 = {0.f,0.f,0.f,0.f};
        f32x4 ol0 = {0.f,0.f,0.f,0.f}, ol1 = {0.f,0.f,0.f,0.f};

        // prologue: tile 0 -> buf 0; tab tile 0 -> c regs (f16 -> f32)
        *(f16x8*)myc0 = *(const f16x8*)(kv);
        f32x4 c0, c1, c2;
        {
            const _Float16* t = tb + (yq + 31) * 768;
            f16x4 t0 = *(const f16x4*)(t);
            f16x4 t1 = *(const f16x4*)(t + 256);
            f16x4 t2 = *(const f16x4*)(t + 512);
#pragma unroll
            for (int r = 0; r < 4; ++r) {
                c0[r] = (float)t0[r]; c1[r] = (float)t1[r]; c2[r] = (float)t2[r];
            }
        }
        __syncthreads();

        int cur = 0;
        for (int kt = 0; kt < 32; ++kt) {
            const bool more = (kt < 31);
            f16x8 stg;
            f16x4 n0v, n1v, n2v;
            if (more) {
                stg = *(const f16x8*)(kv + (kt + 1) * 1024);
                const int d = (yq + 30 - kt) * 768;
                n0v = *(const f16x4*)(tb + d);
                n1v = *(const f16x4*)(tb + d + 256);
                n2v = *(const f16x4*)(tb + d + 512);
            }

            const _Float16* kb = KVb + (cur * 4) * 512;
            const f16x8 kf0 = *(const f16x8*)(kb + 0 * 512 + lane * 8);
            const f16x8 kf1 = *(const f16x8*)(kb + 1 * 512 + lane * 8);
            const f16x8 vf0 = *(const f16x8*)(kb + 2 * 512 + lane * 8);
            const f16x8 vf1 = *(const f16x8*)(kb + 3 * 512 + lane * 8);

            // S^T = K.Q^T with bias C-init (rows = keys, cols = q)
            __builtin_amdgcn_s_setprio(1);
            f32x4 s00 = __builtin_amdgcn_mfma_f32_16x16x32_f16(kf0, qf0, c1, 0, 0, 0);
            f32x4 s01 = __builtin_amdgcn_mfma_f32_16x16x32_f16(kf1, qf0, c0, 0, 0, 0);
            f32x4 s10 = __builtin_amdgcn_mfma_f32_16x16x32_f16(kf0, qf1, c2, 0, 0, 0);
            f32x4 s11 = __builtin_amdgcn_mfma_f32_16x16x32_f16(kf1, qf1, c1, 0, 0, 0);
            __builtin_amdgcn_s_setprio(0);

            _Float16* pw = Ps + (w * 32) * 40;
            f16x4 p;
#pragma unroll
            for (int r = 0; r < 4; ++r) p[r] = (_Float16)__builtin_amdgcn_exp2f(s00[r]);
            *(f16x4*)(pw + l16 * 40 + quad * 4) = p;
#pragma unroll
            for (int r = 0; r < 4; ++r) p[r] = (_Float16)__builtin_amdgcn_exp2f(s01[r]);
            *(f16x4*)(pw + l16 * 40 + 16 + quad * 4) = p;
#pragma unroll
            for (int r = 0; r < 4; ++r) p[r] = (_Float16)__builtin_amdgcn_exp2f(s10[r]);
            *(f16x4*)(pw + (16 + l16) * 40 + quad * 4) = p;
#pragma unroll
            for (int r = 0; r < 4; ++r) p[r] = (_Float16)__builtin_amdgcn_exp2f(s11[r]);
            *(f16x4*)(pw + (16 + l16) * 40 + 16 + quad * 4) = p;

            const f16x8 pf0 = *(const f16x8*)(pw + l16 * 40 + quad * 8);
            const f16x8 pf1 = *(const f16x8*)(pw + (16 + l16) * 40 + quad * 8);
            __builtin_amdgcn_s_setprio(1);
            o00 = __builtin_amdgcn_mfma_f32_16x16x32_f16(vf0, pf0, o00, 0, 0, 0);
            o01 = __builtin_amdgcn_mfma_f32_16x16x32_f16(vf0, pf1, o01, 0, 0, 0);
            o10 = __builtin_amdgcn_mfma_f32_16x16x32_f16(vf1, pf0, o10, 0, 0, 0);
            o11 = __builtin_amdgcn_mfma_f32_16x16x32_f16(vf1, pf1, o11, 0, 0, 0);
            ol0 = __builtin_amdgcn_mfma_f32_16x16x32_f16(ones, pf0, ol0, 0, 0, 0);
            ol1 = __builtin_amdgcn_mfma_f32_16x16x32_f16(ones, pf1, ol1, 0, 0, 0);
            __builtin_amdgcn_s_setprio(0);

            if (more) {
                *(f16x8*)(cur ? myc0 : myc1) = stg;
#pragma unroll
                for (int r = 0; r < 4; ++r) {
                    c0[r] = (float)n0v[r]; c1[r] = (float)n1v[r]; c2[r] = (float)n2v[r];
                }
            }
            __syncthreads();
            cur ^= 1;
        }

        // epilogue: normalize, store xh row-major fp16
#pragma unroll
        for (int qh = 0; qh < 2; ++qh) {
            const f32x4 onl = qh ? o01 : o00;   // hd 0-15
            const f32x4 onh = qh ? o11 : o10;   // hd 16-31
            const f32x4 ll  = qh ? ol1 : ol0;
            const float inv = __builtin_amdgcn_rcpf(ll[0]);
            const int qg = qrow_base + qh * 16 + l16;
            f16x4 u, v;
#pragma unroll
            for (int r = 0; r < 4; ++r) {
                u[r] = (_Float16)(onl[r] * inv);
                v[r] = (_Float16)(onh[r] * inv);
            }
            _Float16* op = xh + ((size_t)(b * S_LEN + qg)) * D_MOD + h * 32 + quad * 4;
            *(f16x4*)(op)      = u;
            *(f16x4*)(op + 16) = v;
        }
    }
    grid_barrier(bar + 2, 512);

    // ============ phase 4: output GEMM ============
    {
        _Float16* As = SMEM;               // [64][264]
        const int m0 = (bid & 127) * 64;
        const int n0 = (bid >> 7) * 64;

        {
            const int r  = tid >> 2;
            const int c8 = (tid & 3) * 8;
            const _Float16* src = xh + (size_t)(m0 + r) * 256 + c8;
            _Float16* dst = As + r * 264 + c8;
#pragma unroll
            for (int g = 0; g < 8; ++g)
                *(f16x8*)(dst + g * 32) = *(const f16x8*)(src + g * 32);
        }
        __syncthreads();

        const int n16base = 48 + (n0 >> 4) + (w >> 1) * 2;
        const _Float16* w0p = wtp + (((size_t)(n16base + 0) * 8) << 9) + lane * 8;
        const _Float16* w1p = wtp + (((size_t)(n16base + 1) * 8) << 9) + lane * 8;
        const _Float16* arow0 = As + ((w & 1) * 32 + l16) * 264;
        const _Float16* arow1 = arow0 + 16 * 264;

        f32x4 acc[2][2];
#pragma unroll
        for (int i = 0; i < 2; ++i)
#pragma unroll
            for (int j = 0; j < 2; ++j) acc[i][j] = (f32x4){0.f, 0.f, 0.f, 0.f};

#pragma unroll
        for (int kk = 0; kk < 8; ++kk) {
            const int k8 = kk * 32 + quad * 8;
            f16x8 a0 = *(const f16x8*)(arow0 + k8);
            f16x8 a1 = *(const f16x8*)(arow1 + k8);
            f16x8 b0 = *(const f16x8*)(w0p + kk * 512);
            f16x8 b1 = *(const f16x8*)(w1p + kk * 512);
            acc[0][0] = __builtin_amdgcn_mfma_f32_16x16x32_f16(a0, b0, acc[0][0], 0, 0, 0);
            acc[0][1] = __builtin_amdgcn_mfma_f32_16x16x32_f16(a0, b1, acc[0][1], 0, 0, 0);
            acc[1][0] = __builtin_amdgcn_mfma_f32_16x16x32_f16(a1, b0, acc[1][0], 0, 0, 0);
            acc[1][1] = __builtin_amdgcn_mfma_f32_16x16x32_f16(a1, b1, acc[1][1], 0, 0, 0);
        }

        // epilogue: fp32 LDS transpose -> coalesced f32x4 stores
        __syncthreads();                   // As fp16 tile dead, reuse as fp32
        {
            float* Tf = (float*)As;        // [64][68] fp32
#pragma unroll
            for (int i = 0; i < 2; ++i) {
#pragma unroll
                for (int jj = 0; jj < 2; ++jj) {
#pragma unroll
                    for (int r = 0; r < 4; ++r) {
                        const int row = (w & 1) * 32 + jj * 16 + quad * 4 + r;
                        const int col = (w >> 1) * 32 + i * 16 + l16;
                        Tf[row * 68 + col] = acc[jj][i][r];
                    }
                }
            }
            __syncthreads();
            const f32x4 bv4 = *(const f32x4*)(bo + n0 + l16 * 4);
#pragma unroll
            for (int g = 0; g < 4; ++g) {
                const int row = w * 16 + g * 4 + quad;
                f32x4 v = *(const f32x4*)(Tf + row * 68 + l16 * 4);
                v += bv4;
                *(f32x4*)(out + (size_t)(m0 + row) * 256 + n0 + l16 * 4) = v;
            }
        }
    }
}

// ---------------------------------------------------------------------------
extern "C" void kernel_launch(void* const* d_in, const int* in_sizes, int n_in,
                              void* d_out, int out_size, void* d_ws, size_t ws_size,
                              hipStream_t stream) {
    const float* in_q  = (const float*)d_in[0];
    const float* in_kv = (const float*)d_in[1];
    const float* Wq    = (const float*)d_in[2];
    const float* bq    = (const float*)d_in[3];
    const float* Wk    = (const float*)d_in[4];
    const float* bk    = (const float*)d_in[5];
    const float* Wv    = (const float*)d_in[6];
    const float* bv    = (const float*)d_in[7];
    const float* rel   = (const float*)d_in[8];
    const float* Wo    = (const float*)d_in[9];
    const float* bo    = (const float*)d_in[10];
    float* out = (float*)d_out;

    char* wsb = (char*)d_ws;
    _Float16* qs  = (_Float16*)(wsb);                         // 4 MB packed Q
    _Float16* ks  = (_Float16*)(wsb + (size_t)4  * 1048576);  // 4 MB packed K
    _Float16* vs  = (_Float16*)(wsb + (size_t)8  * 1048576);  // 4 MB packed V^T
    _Float16* xh  = (_Float16*)(wsb + (size_t)12 * 1048576);  // 4 MB row-major
    _Float16* wtp = (_Float16*)(wsb + (size_t)16 * 1048576);  // 512 KB packed W
    _Float16* tab = (_Float16*)(wsb + (size_t)17 * 1048576);  // 0.78 MB fp16 tab
    int*      bar = (int*)     (wsb + (size_t)19 * 1048576);  // 3 barrier ctrs

    hipMemsetAsync(bar, 0, 3 * sizeof(int), stream);          // per-replay reset
    mega_kernel<<<dim3(512), dim3(256), 0, stream>>>(
        in_q, in_kv, Wq, bq, Wk, bk, Wv, bv, rel, Wo, bo, out,
        qs, ks, vs, xh, wtp, tab, bar);
}

// Round 5
// 128.979 us; speedup vs baseline: 2.4794x; 2.4794x over previous
//
#include <hip/hip_runtime.h>

// Problem constants
#define B_SZ   8
#define S_LEN  1024
#define D_MOD  256
#define NHEADS 8
#define M_ROWS 8192
#define LOG2E  1.4426950408889634f
#define QSCALE_LOG2E 0.2550352766751165f   // (1/sqrt(32)) * log2(e)

typedef _Float16 f16x8 __attribute__((ext_vector_type(8)));
typedef _Float16 f16x4 __attribute__((ext_vector_type(4)));
typedef float    f32x4 __attribute__((ext_vector_type(4)));

// ---------------------------------------------------------------------------
// prep: blocks 0..31  : pack 4 fp32 W mats -> fragment-ordered fp16 wtp.
//       blocks 32..94 : fp16 bias C-init table (one block per dy31):
//        tab[((h*63+dy31)*3+e)*256 + lane*4 + r]
//          = (f16)(rel[(dy31*63 + 16e + l16 - quad*4 - r + 15)*8 + h] * LOG2E)
// ---------------------------------------------------------------------------
__global__ __launch_bounds__(256)
void prep_kernel(const float* __restrict__ Wq, const float* __restrict__ Wk,
                 const float* __restrict__ Wv, const float* __restrict__ Wo,
                 const float* __restrict__ rel,
                 _Float16* __restrict__ wtp, _Float16* __restrict__ tab) {
    if (blockIdx.x < 32) {
        __shared__ _Float16 Wl[32 * 264];
        const int mi = blockIdx.x >> 3;
        const int k0 = (blockIdx.x & 7) << 5;
        const float* W = (mi == 0) ? Wq : (mi == 1) ? Wk : (mi == 2) ? Wv : Wo;
        {
            const int r  = threadIdx.x >> 3;
            const int c4 = (threadIdx.x & 7) * 4;
            const float* src = W + (size_t)(k0 + r) * 256 + c4;
#pragma unroll
            for (int g = 0; g < 8; ++g) {
                f32x4 v = *(const f32x4*)(src + g * 32);
                f16x4 o;
#pragma unroll
                for (int j = 0; j < 4; ++j) o[j] = (_Float16)v[j];
                *(f16x4*)(&Wl[r * 264 + c4 + g * 32]) = o;
            }
        }
        __syncthreads();
        const int n16 = threadIdx.x >> 4;
        const int l16 = threadIdx.x & 15;
        const int kk  = k0 >> 5;
#pragma unroll
        for (int quad = 0; quad < 4; ++quad) {
            f16x8 v;
#pragma unroll
            for (int j = 0; j < 8; ++j) v[j] = Wl[(quad * 8 + j) * 264 + n16 * 16 + l16];
            *(f16x8*)(wtp + (((size_t)(mi * 16 + n16) * 8 + kk) << 9) + (quad * 16 + l16) * 8) = v;
        }
        return;
    }
    __shared__ float rl[63 * 8];
    const int dy31 = blockIdx.x - 32;
    for (int f = threadIdx.x; f < 504; f += 256) rl[f] = rel[(size_t)dy31 * 504 + f];
    __syncthreads();
    const int h  = threadIdx.x >> 5;
    const int r5 = threadIdx.x & 31;
#pragma unroll
    for (int c = 0; c < 6; ++c) {
        const int oi   = r5 * 6 + c;       // 0..191
        const int e    = oi >> 6;
        const int lane = oi & 63;
        const int quad = lane >> 4, l16 = lane & 15;
        f16x4 v;
#pragma unroll
        for (int reg = 0; reg < 4; ++reg) {
            const int idx = 16 * e + l16 - quad * 4 - reg + 15;   // in [0,62]
            v[reg] = (_Float16)(rl[idx * 8 + h] * LOG2E);
        }
        *(f16x4*)(tab + (((size_t)(h * 63 + dy31) * 3 + e) << 8) + lane * 4) = v;
    }
}

// ---------------------------------------------------------------------------
// QKV GEMM (unchanged, round-1 measured form). 1024 blocks, 4 blocks/CU.
// ---------------------------------------------------------------------------
__global__ __launch_bounds__(256)
void gemm_qkv_kernel(const float* __restrict__ in_q, const float* __restrict__ in_kv,
                     const _Float16* __restrict__ wtp,
                     const float* __restrict__ bq, const float* __restrict__ bk,
                     const float* __restrict__ bv,
                     _Float16* __restrict__ qs, _Float16* __restrict__ ks,
                     _Float16* __restrict__ vs) {
    __shared__ __align__(16) _Float16 As[64 * 264];
    _Float16* Ta = As;                 // epilogue tile (Q or K): [act64][hd 72]
    _Float16* Tb = As + 64 * 72;       // epilogue tile V: [hd64][key 72]

    const int tid  = threadIdx.x;
    const int w    = tid >> 6;
    const int lane = tid & 63;
    const int quad = lane >> 4;
    const int l16  = lane & 15;
    const int m0 = blockIdx.x * 64, n0 = blockIdx.y * 64, z = blockIdx.z;
    const int b = m0 >> 10, mloc = m0 & 1023;

    {
        const int r  = tid >> 2;
        const int c4 = (tid & 3) * 4;
        const float* src = (z ? in_kv : in_q) + (size_t)(m0 + r) * 256 + c4;
        _Float16* dst = As + r * 264 + c4;
#pragma unroll
        for (int g = 0; g < 16; ++g) {
            f32x4 v = *(const f32x4*)(src + g * 16);
            f16x4 o;
#pragma unroll
            for (int j = 0; j < 4; ++j) o[j] = (_Float16)v[j];
            *(f16x4*)(dst + g * 16) = o;
        }
    }
    __syncthreads();

    const int n16base = (n0 >> 4) + (w >> 1) * 2;
    const int mA = z ? 1 : 0;
    const _Float16* wA0 = wtp + (((size_t)(mA * 16 + n16base + 0) * 8) << 9) + lane * 8;
    const _Float16* wA1 = wtp + (((size_t)(mA * 16 + n16base + 1) * 8) << 9) + lane * 8;
    const _Float16* wV0 = wtp + (((size_t)(2 * 16 + n16base + 0) * 8) << 9) + lane * 8;
    const _Float16* wV1 = wtp + (((size_t)(2 * 16 + n16base + 1) * 8) << 9) + lane * 8;
    const _Float16* arow0 = As + ((w & 1) * 32 + l16) * 264;
    const _Float16* arow1 = arow0 + 16 * 264;

    f32x4 accA[2][2], accV[2][2];
#pragma unroll
    for (int i = 0; i < 2; ++i)
#pragma unroll
        for (int j = 0; j < 2; ++j) {
            accA[i][j] = (f32x4){0.f, 0.f, 0.f, 0.f};
            accV[i][j] = (f32x4){0.f, 0.f, 0.f, 0.f};
        }

#pragma unroll
    for (int kk = 0; kk < 8; ++kk) {
        const int k8 = kk * 32 + quad * 8;
        f16x8 a0 = *(const f16x8*)(arow0 + k8);
        f16x8 a1 = *(const f16x8*)(arow1 + k8);
        f16x8 w0 = *(const f16x8*)(wA0 + kk * 512);
        f16x8 w1 = *(const f16x8*)(wA1 + kk * 512);
        // swapped: D[m=hd][n=act]
        accA[0][0] = __builtin_amdgcn_mfma_f32_16x16x32_f16(w0, a0, accA[0][0], 0, 0, 0);
        accA[0][1] = __builtin_amdgcn_mfma_f32_16x16x32_f16(w0, a1, accA[0][1], 0, 0, 0);
        accA[1][0] = __builtin_amdgcn_mfma_f32_16x16x32_f16(w1, a0, accA[1][0], 0, 0, 0);
        accA[1][1] = __builtin_amdgcn_mfma_f32_16x16x32_f16(w1, a1, accA[1][1], 0, 0, 0);
        if (z == 1) {
            f16x8 v0 = *(const f16x8*)(wV0 + kk * 512);
            f16x8 v1 = *(const f16x8*)(wV1 + kk * 512);
            // normal: D[m=key][n=hd]
            accV[0][0] = __builtin_amdgcn_mfma_f32_16x16x32_f16(a0, v0, accV[0][0], 0, 0, 0);
            accV[0][1] = __builtin_amdgcn_mfma_f32_16x16x32_f16(a0, v1, accV[0][1], 0, 0, 0);
            accV[1][0] = __builtin_amdgcn_mfma_f32_16x16x32_f16(a1, v0, accV[1][0], 0, 0, 0);
            accV[1][1] = __builtin_amdgcn_mfma_f32_16x16x32_f16(a1, v1, accV[1][1], 0, 0, 0);
        }
    }
    __syncthreads();   // As reuse as Ta/Tb

    {
        const float* biasA = z ? bk : bq;
        const float  sc    = z ? 1.0f : QSCALE_LOG2E;
#pragma unroll
        for (int i = 0; i < 2; ++i) {
            f32x4 b4 = *(const f32x4*)(biasA + n0 + (w >> 1) * 32 + i * 16 + quad * 4);
#pragma unroll
            for (int jj = 0; jj < 2; ++jj) {
                f16x4 pk;
#pragma unroll
                for (int r = 0; r < 4; ++r) pk[r] = (_Float16)((accA[i][jj][r] + b4[r]) * sc);
                *(f16x4*)(Ta + ((w & 1) * 32 + jj * 16 + l16) * 72 +
                               (w >> 1) * 32 + i * 16 + quad * 4) = pk;
            }
        }
        if (z == 1) {
#pragma unroll
            for (int i = 0; i < 2; ++i) {
                const float bvv = bv[n0 + (w >> 1) * 32 + i * 16 + l16];
#pragma unroll
                for (int jj = 0; jj < 2; ++jj) {
                    f16x4 pk;
#pragma unroll
                    for (int r = 0; r < 4; ++r) pk[r] = (_Float16)(accV[jj][i][r] + bvv);
                    *(f16x4*)(Tb + ((w >> 1) * 32 + i * 16 + l16) * 72 +
                                   (w & 1) * 32 + jj * 16 + quad * 4) = pk;
                }
            }
        }
    }
    __syncthreads();
    {
        const int l16c = tid & 15, qdc = (tid >> 4) & 3;
        const int tile0 = mloc >> 5;
#pragma unroll
        for (int c2i = 0; c2i < 2; ++c2i) {
            const int c2 = w * 2 + c2i;
            const int s2 = c2 >> 2, sub = (c2 >> 1) & 1, hs = c2 & 1;
            const int bh = b * 8 + (n0 >> 5) + hs;
            const size_t dbase = (((size_t)(bh * 32 + tile0 + s2) * 2 + sub) << 9) + lane * 8;
            f16x8 va = *(const f16x8*)(Ta + (s2 * 32 + sub * 16 + l16c) * 72 +
                                            hs * 32 + qdc * 8);
            *(f16x8*)((z ? ks : qs) + dbase) = va;
            if (z == 1) {
                f16x8 vb = *(const f16x8*)(Tb + (hs * 32 + sub * 16 + l16c) * 72 +
                                                s2 * 32 + qdc * 8);
                *(f16x8*)(vs + dbase) = vb;
            }
        }
    }
}

// ---------------------------------------------------------------------------
// Output GEMM, NOW 1024 blocks (64x32 tiles) at 4 blocks/CU (2x TLP).
// Each wave: one n16 slice (w>>1), one m-half (w&1); 16 MFMAs.
// Epilogue: fp32 LDS transpose [64][36] -> coalesced f32x4 stores.
// ---------------------------------------------------------------------------
__global__ __launch_bounds__(256, 4)
void gemm_out_kernel(const _Float16* __restrict__ xh, const _Float16* __restrict__ wtp,
                     const float* __restrict__ bo, float* __restrict__ out) {
    __shared__ __align__(16) _Float16 As[64 * 264];
    const int tid  = threadIdx.x;
    const int w    = tid >> 6;
    const int lane = tid & 63;
    const int quad = lane >> 4;
    const int l16  = lane & 15;
    const int m0 = blockIdx.x * 64, n0 = blockIdx.y * 32;

    {
        const int r  = tid >> 2;
        const int c8 = (tid & 3) * 8;
        const _Float16* src = xh + (size_t)(m0 + r) * 256 + c8;
        _Float16* dst = As + r * 264 + c8;
#pragma unroll
        for (int g = 0; g < 8; ++g)
            *(f16x8*)(dst + g * 32) = *(const f16x8*)(src + g * 32);
    }
    __syncthreads();

    const int n16 = 48 + (n0 >> 4) + (w >> 1);
    const _Float16* w0p = wtp + (((size_t)n16 * 8) << 9) + lane * 8;
    const _Float16* arow0 = As + ((w & 1) * 32 + l16) * 264;
    const _Float16* arow1 = arow0 + 16 * 264;

    f32x4 acc0 = {0.f, 0.f, 0.f, 0.f}, acc1 = {0.f, 0.f, 0.f, 0.f};

#pragma unroll
    for (int kk = 0; kk < 8; ++kk) {
        const int k8 = kk * 32 + quad * 8;
        f16x8 a0 = *(const f16x8*)(arow0 + k8);
        f16x8 a1 = *(const f16x8*)(arow1 + k8);
        f16x8 b0 = *(const f16x8*)(w0p + kk * 512);
        acc0 = __builtin_amdgcn_mfma_f32_16x16x32_f16(a0, b0, acc0, 0, 0, 0);
        acc1 = __builtin_amdgcn_mfma_f32_16x16x32_f16(a1, b0, acc1, 0, 0, 0);
    }

    __syncthreads();                       // As fp16 tile dead, reuse as fp32
    {
        float* Tf = (float*)As;            // [64][36] fp32 = 9.2 KB
        const int col = (w >> 1) * 16 + l16;
#pragma unroll
        for (int jj = 0; jj < 2; ++jj) {
            const f32x4 a = jj ? acc1 : acc0;
#pragma unroll
            for (int r = 0; r < 4; ++r) {
                const int row = (w & 1) * 32 + jj * 16 + quad * 4 + r;
                Tf[row * 36 + col] = a[r];
            }
        }
        __syncthreads();
        const int c4 = (tid & 7) * 4;
        const f32x4 bv4 = *(const f32x4*)(bo + n0 + c4);
#pragma unroll
        for (int g = 0; g < 2; ++g) {
            const int row = g * 32 + (tid >> 3);
            f32x4 v = *(const f32x4*)(Tf + row * 36 + c4);
            v += bv4;
            *(f32x4*)(out + (size_t)(m0 + row) * 256 + n0 + c4) = v;
        }
    }
}

// ---------------------------------------------------------------------------
// Flash attention, NOW 1024 blocks (wave = 16 q-rows) at 4 blocks/CU (2x TLP,
// 50% occupancy). Per iter per wave: 2 S-MFMA + 8 exp2 + 3 PV-MFMA (halved
// dep-chain work vs the 512-block version). fp16 bias tab, panel
// e = 1 + qsub - ksub. Reg prefetch, wave-private P round-trip, no barriers.
// ---------------------------------------------------------------------------
__global__ __launch_bounds__(256, 4)
void attn_kernel(const _Float16* __restrict__ qs, const _Float16* __restrict__ ks,
                 const _Float16* __restrict__ vs, const _Float16* __restrict__ tab,
                 _Float16* __restrict__ xh) {
    __shared__ __align__(16) _Float16 Ps[4][16][40];

    const int tid  = threadIdx.x;
    const int w    = tid >> 6;
    const int lane = tid & 63;
    const int quad = lane >> 4;
    const int l16  = lane & 15;

    const int n     = blockIdx.x;
    const int xcd   = n & 7;
    const int local = n >> 3;              // 0..127
    const int bh    = xcd * 8 + (local & 7);
    const int qc    = local >> 3;          // 0..15
    const int b = bh >> 3, h = bh & 7;
    const int t16  = qc * 4 + w;           // 16-row q tile, 0..63
    const int qsub = t16 & 1;
    const int yq   = t16 >> 1;             // image row block, 0..31

    const _Float16* qp = qs + (((size_t)(bh * 32 + (t16 >> 1)) * 2 + qsub) << 9) + lane * 8;
    const f16x8 qf = *(const f16x8*)(qp);

    const _Float16* kp = ks + (((size_t)bh * 64) << 9) + lane * 8;   // +kt*1024
    const _Float16* vp = vs + (((size_t)bh * 64) << 9) + lane * 8;
    const _Float16* tb = tab + (((size_t)h * 189) << 8) + lane * 4;  // +dy31*768
    const int eA = (1 + qsub) << 8;        // panel for ksub=0
    const int eB = qsub << 8;              // panel for ksub=1

    f16x8 ones;
#pragma unroll
    for (int j = 0; j < 8; ++j) ones[j] = (_Float16)1.0f;

    f32x4 olo = {0.f,0.f,0.f,0.f}, ohi = {0.f,0.f,0.f,0.f}, osum = {0.f,0.f,0.f,0.f};

    f16x8 kf0 = *(const f16x8*)(kp);
    f16x8 kf1 = *(const f16x8*)(kp + 512);
    f16x8 vf0 = *(const f16x8*)(vp);
    f16x8 vf1 = *(const f16x8*)(vp + 512);
    f32x4 cA, cB;
    {
        const int d = (yq + 31) * 768;
        f16x4 tA = *(const f16x4*)(tb + d + eA);
        f16x4 tB = *(const f16x4*)(tb + d + eB);
#pragma unroll
        for (int r = 0; r < 4; ++r) { cA[r] = (float)tA[r]; cB[r] = (float)tB[r]; }
    }

    for (int kt = 0; kt < 32; ++kt) {
        const bool more = (kt < 31);
        f16x8 nk0, nk1, nv0, nv1;
        f16x4 tA, tB;
        if (more) {
            const _Float16* kq = kp + (kt + 1) * 1024;
            nk0 = *(const f16x8*)(kq);
            nk1 = *(const f16x8*)(kq + 512);
            const _Float16* vq = vp + (kt + 1) * 1024;
            nv0 = *(const f16x8*)(vq);
            nv1 = *(const f16x8*)(vq + 512);
            const int d = (yq + 30 - kt) * 768;
            tA = *(const f16x4*)(tb + d + eA);
            tB = *(const f16x4*)(tb + d + eB);
        }

        // S^T = K.Q^T with bias C-init (rows = keys 0-31, cols = q 0-15)
        __builtin_amdgcn_s_setprio(1);
        f32x4 s0 = __builtin_amdgcn_mfma_f32_16x16x32_f16(kf0, qf, cA, 0, 0, 0);
        f32x4 s1 = __builtin_amdgcn_mfma_f32_16x16x32_f16(kf1, qf, cB, 0, 0, 0);
        __builtin_amdgcn_s_setprio(0);

        f16x4 p;
#pragma unroll
        for (int r = 0; r < 4; ++r) p[r] = (_Float16)__builtin_amdgcn_exp2f(s0[r]);
        *(f16x4*)(&Ps[w][l16][quad * 4]) = p;
#pragma unroll
        for (int r = 0; r < 4; ++r) p[r] = (_Float16)__builtin_amdgcn_exp2f(s1[r]);
        *(f16x4*)(&Ps[w][l16][16 + quad * 4]) = p;

        const f16x8 pf = *(const f16x8*)(&Ps[w][l16][quad * 8]);
        __builtin_amdgcn_s_setprio(1);
        olo  = __builtin_amdgcn_mfma_f32_16x16x32_f16(vf0, pf, olo, 0, 0, 0);
        ohi  = __builtin_amdgcn_mfma_f32_16x16x32_f16(vf1, pf, ohi, 0, 0, 0);
        osum = __builtin_amdgcn_mfma_f32_16x16x32_f16(ones, pf, osum, 0, 0, 0);
        __builtin_amdgcn_s_setprio(0);

        if (more) {
            kf0 = nk0; kf1 = nk1; vf0 = nv0; vf1 = nv1;
#pragma unroll
            for (int r = 0; r < 4; ++r) { cA[r] = (float)tA[r]; cB[r] = (float)tB[r]; }
        }
    }

    // epilogue: normalize, store xh row-major fp16
    const float inv = __builtin_amdgcn_rcpf(osum[0]);
    const int qg = t16 * 16 + l16;
    f16x4 u, v;
#pragma unroll
    for (int r = 0; r < 4; ++r) {
        u[r] = (_Float16)(olo[r] * inv);
        v[r] = (_Float16)(ohi[r] * inv);
    }
    _Float16* op = xh + ((size_t)(b * S_LEN + qg)) * D_MOD + h * 32 + quad * 4;
    *(f16x4*)(op)      = u;
    *(f16x4*)(op + 16) = v;
}

// ---------------------------------------------------------------------------
extern "C" void kernel_launch(void* const* d_in, const int* in_sizes, int n_in,
                              void* d_out, int out_size, void* d_ws, size_t ws_size,
                              hipStream_t stream) {
    const float* in_q  = (const float*)d_in[0];
    const float* in_kv = (const float*)d_in[1];
    const float* Wq    = (const float*)d_in[2];
    const float* bq    = (const float*)d_in[3];
    const float* Wk    = (const float*)d_in[4];
    const float* bk    = (const float*)d_in[5];
    const float* Wv    = (const float*)d_in[6];
    const float* bv    = (const float*)d_in[7];
    const float* rel   = (const float*)d_in[8];
    const float* Wo    = (const float*)d_in[9];
    const float* bo    = (const float*)d_in[10];
    float* out = (float*)d_out;

    char* wsb = (char*)d_ws;
    _Float16* qs  = (_Float16*)(wsb);                         // 4 MB packed Q
    _Float16* ks  = (_Float16*)(wsb + (size_t)4  * 1048576);  // 4 MB packed K
    _Float16* vs  = (_Float16*)(wsb + (size_t)8  * 1048576);  // 4 MB packed V^T
    _Float16* xh  = (_Float16*)(wsb + (size_t)12 * 1048576);  // 4 MB row-major
    _Float16* wtp = (_Float16*)(wsb + (size_t)16 * 1048576);  // 512 KB packed W
    _Float16* tab = (_Float16*)(wsb + (size_t)17 * 1048576);  // 0.78 MB fp16 tab

    const dim3 blk(256);

    prep_kernel<<<dim3(95), blk, 0, stream>>>(Wq, Wk, Wv, Wo, rel, wtp, tab);
    gemm_qkv_kernel<<<dim3(128, 4, 2), blk, 0, stream>>>(
        in_q, in_kv, wtp, bq, bk, bv, qs, ks, vs);
    attn_kernel<<<dim3(1024), blk, 0, stream>>>(qs, ks, vs, tab, xh);
    gemm_out_kernel<<<dim3(128, 8), blk, 0, stream>>>(xh, wtp, bo, out);
}

// Round 6
// 122.627 us; speedup vs baseline: 2.6078x; 1.0518x over previous
//
#include <hip/hip_runtime.h>

// Problem constants
#define B_SZ   8
#define S_LEN  1024
#define D_MOD  256
#define NHEADS 8
#define M_ROWS 8192
#define LOG2E  1.4426950408889634f
#define QSCALE_LOG2E 0.2550352766751165f   // (1/sqrt(32)) * log2(e)

typedef _Float16 f16x8 __attribute__((ext_vector_type(8)));
typedef _Float16 f16x4 __attribute__((ext_vector_type(4)));
typedef float    f32x4 __attribute__((ext_vector_type(4)));

// ---------------------------------------------------------------------------
// prep: blocks 0..31  : pack 4 fp32 W mats -> fragment-ordered fp16 wtp.
//        wtp[(mat*16+n16)*8+kk][lane][8] : val = W[kk*32 + (lane>>4)*8 + j]
//                                              [n16*16 + (lane&15)]
//       blocks 32..94 : bias C-init table (LDS-staged rel rows, coalesced out)
//        tab[((h*63+dy31)*3+e)*256 + lane*4 + r]
//          = rel[(dy31*63 + 16e + l16 - quad*4 - r + 15)*8 + h] * LOG2E
// ---------------------------------------------------------------------------
__global__ __launch_bounds__(256)
void prep_kernel(const float* __restrict__ Wq, const float* __restrict__ Wk,
                 const float* __restrict__ Wv, const float* __restrict__ Wo,
                 const float* __restrict__ rel,
                 _Float16* __restrict__ wtp, float* __restrict__ tab) {
    if (blockIdx.x < 32) {
        __shared__ _Float16 Wl[32 * 264];
        const int mi = blockIdx.x >> 3;
        const int k0 = (blockIdx.x & 7) << 5;
        const float* W = (mi == 0) ? Wq : (mi == 1) ? Wk : (mi == 2) ? Wv : Wo;
        // stage 32 k-rows x 256 n-cols, coalesced
        {
            const int r  = threadIdx.x >> 3;
            const int c4 = (threadIdx.x & 7) * 4;
            const float* src = W + (size_t)(k0 + r) * 256 + c4;
#pragma unroll
            for (int g = 0; g < 8; ++g) {
                f32x4 v = *(const f32x4*)(src + g * 32);
                f16x4 o;
#pragma unroll
                for (int j = 0; j < 4; ++j) o[j] = (_Float16)v[j];
                *(f16x4*)(&Wl[r * 264 + c4 + g * 32]) = o;
            }
        }
        __syncthreads();
        // emit fragment-packed wtp (kk = k0>>5 fixed for this block)
        const int n16 = threadIdx.x >> 4;
        const int l16 = threadIdx.x & 15;
        const int kk  = k0 >> 5;
#pragma unroll
        for (int quad = 0; quad < 4; ++quad) {
            f16x8 v;
#pragma unroll
            for (int j = 0; j < 8; ++j) v[j] = Wl[(quad * 8 + j) * 264 + n16 * 16 + l16];
            *(f16x8*)(wtp + (((size_t)(mi * 16 + n16) * 8 + kk) << 9) + (quad * 16 + l16) * 8) = v;
        }
        return;
    }
    // tab build: one block per dy31
    __shared__ float rl[63 * 8];
    const int dy31 = blockIdx.x - 32;
    for (int f = threadIdx.x; f < 504; f += 256) rl[f] = rel[(size_t)dy31 * 504 + f];
    __syncthreads();
    const int h  = threadIdx.x >> 5;
    const int r5 = threadIdx.x & 31;
#pragma unroll
    for (int c = 0; c < 6; ++c) {
        const int oi   = r5 * 6 + c;       // 0..191
        const int e    = oi >> 6;
        const int lane = oi & 63;
        const int quad = lane >> 4, l16 = lane & 15;
        f32x4 v;
#pragma unroll
        for (int reg = 0; reg < 4; ++reg) {
            const int idx = 16 * e + l16 - quad * 4 - reg + 15;   // in [0,62]
            v[reg] = rl[idx * 8 + h] * LOG2E;
        }
        *(f32x4*)(tab + (((size_t)(h * 63 + dy31) * 3 + e) << 8) + lane * 4) = v;
    }
}

// ---------------------------------------------------------------------------
// QKV GEMM. A staged to LDS (coalesced); B streamed from frag-packed wtp.
// z=0: Q (swapped operands -> D=Q^T, packed qs epilogue, scale folded).
// z=1: K (swapped -> packed ks) + V (normal -> packed vs), sharing the A tile.
// Packed layout: xs[((bh*32 + t)*2 + sub)*512 + lane*8]:
//   qs/ks: lane -> (row = t*32 + sub*16 + (lane&15), hd = (lane>>4)*8 + j)
//   vs:    lane -> (hd  = sub*16 + (lane&15),  key = t*32 + (lane>>4)*8 + j)
// ---------------------------------------------------------------------------
__global__ __launch_bounds__(256)
void gemm_qkv_kernel(const float* __restrict__ in_q, const float* __restrict__ in_kv,
                     const _Float16* __restrict__ wtp,
                     const float* __restrict__ bq, const float* __restrict__ bk,
                     const float* __restrict__ bv,
                     _Float16* __restrict__ qs, _Float16* __restrict__ ks,
                     _Float16* __restrict__ vs) {
    __shared__ __align__(16) _Float16 As[64 * 264];
    _Float16* Ta = As;                 // epilogue tile (Q or K): [act64][hd 72]
    _Float16* Tb = As + 64 * 72;       // epilogue tile V: [hd64][key 72]

    const int tid  = threadIdx.x;
    const int w    = tid >> 6;
    const int lane = tid & 63;
    const int quad = lane >> 4;
    const int l16  = lane & 15;
    const int m0 = blockIdx.x * 64, n0 = blockIdx.y * 64, z = blockIdx.z;
    const int b = m0 >> 10, mloc = m0 & 1023;

    // stage A tile 64x256 fp32 -> fp16 (16-line coalesced loads)
    {
        const int r  = tid >> 2;
        const int c4 = (tid & 3) * 4;
        const float* src = (z ? in_kv : in_q) + (size_t)(m0 + r) * 256 + c4;
        _Float16* dst = As + r * 264 + c4;
#pragma unroll
        for (int g = 0; g < 16; ++g) {
            f32x4 v = *(const f32x4*)(src + g * 16);
            f16x4 o;
#pragma unroll
            for (int j = 0; j < 4; ++j) o[j] = (_Float16)v[j];
            *(f16x4*)(dst + g * 16) = o;
        }
    }
    __syncthreads();

    const int n16base = (n0 >> 4) + (w >> 1) * 2;
    const int mA = z ? 1 : 0;
    const _Float16* wA0 = wtp + (((size_t)(mA * 16 + n16base + 0) * 8) << 9) + lane * 8;
    const _Float16* wA1 = wtp + (((size_t)(mA * 16 + n16base + 1) * 8) << 9) + lane * 8;
    const _Float16* wV0 = wtp + (((size_t)(2 * 16 + n16base + 0) * 8) << 9) + lane * 8;
    const _Float16* wV1 = wtp + (((size_t)(2 * 16 + n16base + 1) * 8) << 9) + lane * 8;
    const _Float16* arow0 = As + ((w & 1) * 32 + l16) * 264;
    const _Float16* arow1 = arow0 + 16 * 264;

    f32x4 accA[2][2], accV[2][2];
#pragma unroll
    for (int i = 0; i < 2; ++i)
#pragma unroll
        for (int j = 0; j < 2; ++j) {
            accA[i][j] = (f32x4){0.f, 0.f, 0.f, 0.f};
            accV[i][j] = (f32x4){0.f, 0.f, 0.f, 0.f};
        }

#pragma unroll
    for (int kk = 0; kk < 8; ++kk) {
        const int k8 = kk * 32 + quad * 8;
        f16x8 a0 = *(const f16x8*)(arow0 + k8);
        f16x8 a1 = *(const f16x8*)(arow1 + k8);
        f16x8 w0 = *(const f16x8*)(wA0 + kk * 512);
        f16x8 w1 = *(const f16x8*)(wA1 + kk * 512);
        // swapped: D[m=hd][n=act]
        accA[0][0] = __builtin_amdgcn_mfma_f32_16x16x32_f16(w0, a0, accA[0][0], 0, 0, 0);
        accA[0][1] = __builtin_amdgcn_mfma_f32_16x16x32_f16(w0, a1, accA[0][1], 0, 0, 0);
        accA[1][0] = __builtin_amdgcn_mfma_f32_16x16x32_f16(w1, a0, accA[1][0], 0, 0, 0);
        accA[1][1] = __builtin_amdgcn_mfma_f32_16x16x32_f16(w1, a1, accA[1][1], 0, 0, 0);
        if (z == 1) {
            f16x8 v0 = *(const f16x8*)(wV0 + kk * 512);
            f16x8 v1 = *(const f16x8*)(wV1 + kk * 512);
            // normal: D[m=key][n=hd]
            accV[0][0] = __builtin_amdgcn_mfma_f32_16x16x32_f16(a0, v0, accV[0][0], 0, 0, 0);
            accV[0][1] = __builtin_amdgcn_mfma_f32_16x16x32_f16(a0, v1, accV[0][1], 0, 0, 0);
            accV[1][0] = __builtin_amdgcn_mfma_f32_16x16x32_f16(a1, v0, accV[1][0], 0, 0, 0);
            accV[1][1] = __builtin_amdgcn_mfma_f32_16x16x32_f16(a1, v1, accV[1][1], 0, 0, 0);
        }
    }
    __syncthreads();   // As reuse as Ta/Tb

    // ---- epilogue: bias + LDS transpose round-trip -> packed stores ----
    {
        const float* biasA = z ? bk : bq;
        const float  sc    = z ? 1.0f : QSCALE_LOG2E;
#pragma unroll
        for (int i = 0; i < 2; ++i) {
            f32x4 b4 = *(const f32x4*)(biasA + n0 + (w >> 1) * 32 + i * 16 + quad * 4);
#pragma unroll
            for (int jj = 0; jj < 2; ++jj) {
                f16x4 pk;
#pragma unroll
                for (int r = 0; r < 4; ++r) pk[r] = (_Float16)((accA[i][jj][r] + b4[r]) * sc);
                *(f16x4*)(Ta + ((w & 1) * 32 + jj * 16 + l16) * 72 +
                               (w >> 1) * 32 + i * 16 + quad * 4) = pk;
            }
        }
        if (z == 1) {
#pragma unroll
            for (int i = 0; i < 2; ++i) {
                const float bvv = bv[n0 + (w >> 1) * 32 + i * 16 + l16];
#pragma unroll
                for (int jj = 0; jj < 2; ++jj) {
                    f16x4 pk;
#pragma unroll
                    for (int r = 0; r < 4; ++r) pk[r] = (_Float16)(accV[jj][i][r] + bvv);
                    *(f16x4*)(Tb + ((w >> 1) * 32 + i * 16 + l16) * 72 +
                                   (w & 1) * 32 + jj * 16 + quad * 4) = pk;
                }
            }
        }
    }
    __syncthreads();
    {
        const int l16c = tid & 15, qdc = (tid >> 4) & 3;
        const int tile0 = mloc >> 5;
#pragma unroll
        for (int c2i = 0; c2i < 2; ++c2i) {
            const int c2 = w * 2 + c2i;
            const int s2 = c2 >> 2, sub = (c2 >> 1) & 1, hs = c2 & 1;
            const int bh = b * 8 + (n0 >> 5) + hs;
            const size_t dbase = (((size_t)(bh * 32 + tile0 + s2) * 2 + sub) << 9) + lane * 8;
            f16x8 va = *(const f16x8*)(Ta + (s2 * 32 + sub * 16 + l16c) * 72 +
                                            hs * 32 + qdc * 8);
            *(f16x8*)((z ? ks : qs) + dbase) = va;
            if (z == 1) {
                f16x8 vb = *(const f16x8*)(Tb + (hs * 32 + sub * 16 + l16c) * 72 +
                                                s2 * 32 + qdc * 8);
                *(f16x8*)(vs + dbase) = vb;
            }
        }
    }
}

// ---------------------------------------------------------------------------
// Output GEMM: A = xh (row-major fp16) staged to LDS; B = wtp[mat 3] stream.
// ---------------------------------------------------------------------------
__global__ __launch_bounds__(256)
void gemm_out_kernel(const _Float16* __restrict__ xh, const _Float16* __restrict__ wtp,
                     const float* __restrict__ bo, float* __restrict__ out) {
    __shared__ __align__(16) _Float16 As[64 * 264];
    const int tid  = threadIdx.x;
    const int w    = tid >> 6;
    const int lane = tid & 63;
    const int quad = lane >> 4;
    const int l16  = lane & 15;
    const int m0 = blockIdx.x * 64, n0 = blockIdx.y * 64;

    {
        const int r  = tid >> 2;
        const int c8 = (tid & 3) * 8;
        const _Float16* src = xh + (size_t)(m0 + r) * 256 + c8;
        _Float16* dst = As + r * 264 + c8;
#pragma unroll
        for (int g = 0; g < 8; ++g)
            *(f16x8*)(dst + g * 32) = *(const f16x8*)(src + g * 32);
    }
    __syncthreads();

    const int n16base = 48 + (n0 >> 4) + (w >> 1) * 2;
    const _Float16* w0p = wtp + (((size_t)(n16base + 0) * 8) << 9) + lane * 8;
    const _Float16* w1p = wtp + (((size_t)(n16base + 1) * 8) << 9) + lane * 8;
    const _Float16* arow0 = As + ((w & 1) * 32 + l16) * 264;
    const _Float16* arow1 = arow0 + 16 * 264;

    f32x4 acc[2][2];
#pragma unroll
    for (int i = 0; i < 2; ++i)
#pragma unroll
        for (int j = 0; j < 2; ++j) acc[i][j] = (f32x4){0.f, 0.f, 0.f, 0.f};

#pragma unroll
    for (int kk = 0; kk < 8; ++kk) {
        const int k8 = kk * 32 + quad * 8;
        f16x8 a0 = *(const f16x8*)(arow0 + k8);
        f16x8 a1 = *(const f16x8*)(arow1 + k8);
        f16x8 b0 = *(const f16x8*)(w0p + kk * 512);
        f16x8 b1 = *(const f16x8*)(w1p + kk * 512);
        acc[0][0] = __builtin_amdgcn_mfma_f32_16x16x32_f16(a0, b0, acc[0][0], 0, 0, 0);
        acc[0][1] = __builtin_amdgcn_mfma_f32_16x16x32_f16(a0, b1, acc[0][1], 0, 0, 0);
        acc[1][0] = __builtin_amdgcn_mfma_f32_16x16x32_f16(a1, b0, acc[1][0], 0, 0, 0);
        acc[1][1] = __builtin_amdgcn_mfma_f32_16x16x32_f16(a1, b1, acc[1][1], 0, 0, 0);
    }

#pragma unroll
    for (int i = 0; i < 2; ++i) {
        const int col = n0 + (w >> 1) * 32 + i * 16 + l16;
        const float bvv = bo[col];
#pragma unroll
        for (int jj = 0; jj < 2; ++jj) {
#pragma unroll
            for (int r = 0; r < 4; ++r) {
                const int row = m0 + (w & 1) * 32 + jj * 16 + quad * 4 + r;
                out[(size_t)row * 256 + col] = acc[jj][i][r] + bvv;
            }
        }
    }
}

// ---------------------------------------------------------------------------
// Flash attention: fragment-packed streams, transposed dataflow, fixed-max
// softmax, tab C-init bias, ones-MFMA row sums, wave-private P round-trip,
// ZERO barriers. grid 512 (XCD-swizzled), 4 waves, wave = 32 q-rows.
// ---------------------------------------------------------------------------
__global__ __launch_bounds__(256)
void attn_kernel(const _Float16* __restrict__ qs, const _Float16* __restrict__ ks,
                 const _Float16* __restrict__ vs, const float* __restrict__ tab,
                 _Float16* __restrict__ xh) {
    __shared__ __align__(16) _Float16 Ps[4][32][40];

    const int tid  = threadIdx.x;
    const int w    = tid >> 6;
    const int lane = tid & 63;
    const int quad = lane >> 4;
    const int l16  = lane & 15;

    const int n     = blockIdx.x;
    const int xcd   = n & 7;
    const int local = n >> 3;
    const int bh    = xcd * 8 + (local & 7);
    const int qc    = local >> 3;          // 0..7
    const int b = bh >> 3, h = bh & 7;
    const int qrow_base = qc * 128 + w * 32;
    const int yq = qc * 4 + w;             // q y-tile

    const _Float16* qp = qs + (((size_t)(bh * 32 + yq) * 2) << 9) + lane * 8;
    const f16x8 qf0 = *(const f16x8*)(qp);
    const f16x8 qf1 = *(const f16x8*)(qp + 512);
    const _Float16* kp = ks + (((size_t)bh * 64) << 9) + lane * 8;   // +kt*1024
    const _Float16* vp = vs + (((size_t)bh * 64) << 9) + lane * 8;
    const float* tb = tab + (((size_t)h * 63 * 3) << 8) + lane * 4;  // +dy31*768

    f16x8 ones;
#pragma unroll
    for (int j = 0; j < 8; ++j) ones[j] = (_Float16)1.0f;

    f32x4 o00 = {0.f,0.f,0.f,0.f}, o01 = {0.f,0.f,0.f,0.f};
    f32x4 o10 = {0.f,0.f,0.f,0.f}, o11 = {0.f,0.f,0.f,0.f};
    f32x4 ol0 = {0.f,0.f,0.f,0.f}, ol1 = {0.f,0.f,0.f,0.f};

    f16x8 kf0 = *(const f16x8*)(kp);
    f16x8 kf1 = *(const f16x8*)(kp + 512);
    f16x8 vf0 = *(const f16x8*)(vp);
    f16x8 vf1 = *(const f16x8*)(vp + 512);
    f32x4 c0 = *(const f32x4*)(tb + (yq + 31) * 768);
    f32x4 c1 = *(const f32x4*)(tb + (yq + 31) * 768 + 256);
    f32x4 c2 = *(const f32x4*)(tb + (yq + 31) * 768 + 512);

    for (int kt = 0; kt < 32; ++kt) {
        const bool more = (kt < 31);
        f16x8 nk0, nk1, nv0, nv1;
        f32x4 nc0, nc1, nc2;
        if (more) {
            const _Float16* kq = kp + (kt + 1) * 1024;
            nk0 = *(const f16x8*)(kq);
            nk1 = *(const f16x8*)(kq + 512);
            const _Float16* vq = vp + (kt + 1) * 1024;
            nv0 = *(const f16x8*)(vq);
            nv1 = *(const f16x8*)(vq + 512);
            const int d = (yq + 30 - kt) * 768;
            nc0 = *(const f32x4*)(tb + d);
            nc1 = *(const f32x4*)(tb + d + 256);
            nc2 = *(const f32x4*)(tb + d + 512);
        }

        // S^T = K.Q^T with bias C-init (rows = keys, cols = q)
        f32x4 s00 = __builtin_amdgcn_mfma_f32_16x16x32_f16(kf0, qf0, c1, 0, 0, 0);
        f32x4 s01 = __builtin_amdgcn_mfma_f32_16x16x32_f16(kf1, qf0, c0, 0, 0, 0);
        f32x4 s10 = __builtin_amdgcn_mfma_f32_16x16x32_f16(kf0, qf1, c2, 0, 0, 0);
        f32x4 s11 = __builtin_amdgcn_mfma_f32_16x16x32_f16(kf1, qf1, c1, 0, 0, 0);

        f16x4 p;
#pragma unroll
        for (int r = 0; r < 4; ++r) p[r] = (_Float16)__builtin_amdgcn_exp2f(s00[r]);
        *(f16x4*)(&Ps[w][l16][quad * 4]) = p;
#pragma unroll
        for (int r = 0; r < 4; ++r) p[r] = (_Float16)__builtin_amdgcn_exp2f(s01[r]);
        *(f16x4*)(&Ps[w][l16][16 + quad * 4]) = p;
#pragma unroll
        for (int r = 0; r < 4; ++r) p[r] = (_Float16)__builtin_amdgcn_exp2f(s10[r]);
        *(f16x4*)(&Ps[w][16 + l16][quad * 4]) = p;
#pragma unroll
        for (int r = 0; r < 4; ++r) p[r] = (_Float16)__builtin_amdgcn_exp2f(s11[r]);
        *(f16x4*)(&Ps[w][16 + l16][16 + quad * 4]) = p;

        const f16x8 pf0 = *(const f16x8*)(&Ps[w][l16][quad * 8]);
        const f16x8 pf1 = *(const f16x8*)(&Ps[w][16 + l16][quad * 8]);
        o00 = __builtin_amdgcn_mfma_f32_16x16x32_f16(vf0, pf0, o00, 0, 0, 0);
        o01 = __builtin_amdgcn_mfma_f32_16x16x32_f16(vf0, pf1, o01, 0, 0, 0);
        o10 = __builtin_amdgcn_mfma_f32_16x16x32_f16(vf1, pf0, o10, 0, 0, 0);
        o11 = __builtin_amdgcn_mfma_f32_16x16x32_f16(vf1, pf1, o11, 0, 0, 0);
        ol0 = __builtin_amdgcn_mfma_f32_16x16x32_f16(ones, pf0, ol0, 0, 0, 0);
        ol1 = __builtin_amdgcn_mfma_f32_16x16x32_f16(ones, pf1, ol1, 0, 0, 0);

        if (more) {
            kf0 = nk0; kf1 = nk1; vf0 = nv0; vf1 = nv1;
            c0 = nc0; c1 = nc1; c2 = nc2;
        }
    }

    // epilogue: normalize, store xh row-major fp16
#pragma unroll
    for (int qh = 0; qh < 2; ++qh) {
        const f32x4 onl = qh ? o01 : o00;   // hd 0-15
        const f32x4 onh = qh ? o11 : o10;   // hd 16-31
        const f32x4 ll  = qh ? ol1 : ol0;
        const float inv = __builtin_amdgcn_rcpf(ll[0]);
        const int qg = qrow_base + qh * 16 + l16;
        f16x4 u, v;
#pragma unroll
        for (int r = 0; r < 4; ++r) {
            u[r] = (_Float16)(onl[r] * inv);
            v[r] = (_Float16)(onh[r] * inv);
        }
        _Float16* op = xh + ((size_t)(b * S_LEN + qg)) * D_MOD + h * 32 + quad * 4;
        *(f16x4*)(op)      = u;
        *(f16x4*)(op + 16) = v;
    }
}

// ---------------------------------------------------------------------------
extern "C" void kernel_launch(void* const* d_in, const int* in_sizes, int n_in,
                              void* d_out, int out_size, void* d_ws, size_t ws_size,
                              hipStream_t stream) {
    const float* in_q  = (const float*)d_in[0];
    const float* in_kv = (const float*)d_in[1];
    const float* Wq    = (const float*)d_in[2];
    const float* bq    = (const float*)d_in[3];
    const float* Wk    = (const float*)d_in[4];
    const float* bk    = (const float*)d_in[5];
    const float* Wv    = (const float*)d_in[6];
    const float* bv    = (const float*)d_in[7];
    const float* rel   = (const float*)d_in[8];
    const float* Wo    = (const float*)d_in[9];
    const float* bo    = (const float*)d_in[10];
    float* out = (float*)d_out;

    char* wsb = (char*)d_ws;
    _Float16* qs  = (_Float16*)(wsb);                         // 4 MB packed Q
    _Float16* ks  = (_Float16*)(wsb + (size_t)4  * 1048576);  // 4 MB packed K
    _Float16* vs  = (_Float16*)(wsb + (size_t)8  * 1048576);  // 4 MB packed V^T
    _Float16* xh  = (_Float16*)(wsb + (size_t)12 * 1048576);  // 4 MB row-major
    _Float16* wtp = (_Float16*)(wsb + (size_t)16 * 1048576);  // 512 KB packed W
    float*    tab = (float*)   (wsb + (size_t)17 * 1048576);  // 1.55 MB bias tab

    const dim3 blk(256);

    prep_kernel<<<dim3(95), blk, 0, stream>>>(Wq, Wk, Wv, Wo, rel, wtp, tab);
    gemm_qkv_kernel<<<dim3(128, 4, 2), blk, 0, stream>>>(
        in_q, in_kv, wtp, bq, bk, bv, qs, ks, vs);
    attn_kernel<<<dim3(512), blk, 0, stream>>>(qs, ks, vs, tab, xh);
    gemm_out_kernel<<<dim3(128, 4), blk, 0, stream>>>(xh, wtp, bo, out);
}